// Round 1
// baseline (77.516 us; speedup 1.0000x reference)
//
#include <hip/hip_runtime.h>

// CP embedding: out[t, emb] = sum_r U0[a,r]U1[b,r]U2[c,r] * U3[d,r]U4[e,r]U5[f,r]
// where x[t] = a*1000 + b*25 + c  (a<50,b<40,c<25), emb = d*64 + e*8 + f.
// Rows with x[t]==0 (padding) are zero.
//
// Shapes: U0 (50,32) U1 (40,32) U2 (25,32) U3/U4/U5 (8,32), x (4,2048) int32,
// out (8192, 512) fp32.
//
// R3: rank-split phase 3 (wt[16] instead of wt[32]) to cut VGPRs ~170 -> ~110,
// __launch_bounds__(256,4) => 4 waves/SIMD, whole 1024-block grid co-resident
// (was 2 waves/SIMD -> two sequential block rounds). Same FLOPs, same LDS
// traffic, same store pattern.

#define RANK 32
#define EMB 512
#define TOK_PER_BLK 32
#define EMB_CHUNK 128

__global__ __launch_bounds__(256, 4) void cp_embed_kernel(
    const float* __restrict__ U0, const float* __restrict__ U1,
    const float* __restrict__ U2, const float* __restrict__ U3,
    const float* __restrict__ U4, const float* __restrict__ U5,
    const int*   __restrict__ x,  float* __restrict__ out)
{
    __shared__ float Wlds[RANK][EMB_CHUNK];     // [r][e_local] slice of W345^T
    __shared__ float wlds[TOK_PER_BLK][RANK];   // [t_local][r] token rank-vectors

    const int tid = threadIdx.x;
    const int c   = blockIdx.x & 3;   // emb chunk: [c*128, c*128+128)
    const int g   = blockIdx.x >> 2;  // token group: [g*32, g*32+32)

    // ---- Phase 1: build this block's 32x128 slice of W345^T in LDS ----
    // quad-aligned e shares d and e2 -> factor s = U3*U4 once per quad
    #pragma unroll
    for (int k = 0; k < 4; ++k) {
        int qd = tid + k * 256;           // quad id 0..1023
        int r  = qd >> 5;                 // rank 0..31
        int e  = (qd & 31) * 4;           // emb-local 0..124, quad-aligned
        int eg = c * EMB_CHUNK + e;       // global emb index (quad-aligned)
        int d  = eg >> 6;
        int e2 = (eg >> 3) & 7;
        int f0 = eg & 7;                  // 0 or 4
        float s = U3[d * RANK + r] * U4[e2 * RANK + r];
        float4 wv;
        wv.x = s * U5[(f0 + 0) * RANK + r];
        wv.y = s * U5[(f0 + 1) * RANK + r];
        wv.z = s * U5[(f0 + 2) * RANK + r];
        wv.w = s * U5[(f0 + 3) * RANK + r];
        *reinterpret_cast<float4*>(&Wlds[r][e]) = wv;
    }

    // ---- Phase 2: build the group's 32 token rank-vectors in LDS ----
    #pragma unroll
    for (int k = 0; k < 4; ++k) {
        int i  = tid + k * 256;           // 0..1023
        int tl = i >> 5;
        int r  = i & 31;
        int v  = x[g * TOK_PER_BLK + tl];
        float wv = 0.0f;
        if (v != 0) {                     // padding_idx = 0 -> zero row
            int a   = v / 1000;
            int rem = v - a * 1000;
            int b   = rem / 25;
            int cc  = rem - b * 25;
            wv = U0[a * RANK + r] * U1[b * RANK + r] * U2[cc * RANK + r];
        }
        wlds[tl][r] = wv;
    }

    __syncthreads();

    // ---- Phase 3: fixed float4 emb-slice per thread; rank dim in 2 halves ----
    const int eq = (tid & 31) * 4;        // emb offset within chunk (0..124)
    const int ts = tid >> 5;              // token sub-slice 0..7

    float4 acc[4];
    #pragma unroll
    for (int k = 0; k < 4; ++k) acc[k] = make_float4(0.f, 0.f, 0.f, 0.f);

    #pragma unroll
    for (int h = 0; h < 2; ++h) {
        float4 wt[16];                    // 64 VGPRs: half of the W345^T column slice
        #pragma unroll
        for (int r = 0; r < 16; ++r)
            wt[r] = *reinterpret_cast<const float4*>(&Wlds[h * 16 + r][eq]);

        #pragma unroll
        for (int k = 0; k < 4; ++k) {
            int tt = ts + k * 8;
            const float4* w4 = reinterpret_cast<const float4*>(wlds[tt]) + h * 4;
            #pragma unroll
            for (int rr = 0; rr < 4; ++rr) {
                float4 wv = w4[rr];
                const float4& w0 = wt[4 * rr + 0];
                const float4& w1 = wt[4 * rr + 1];
                const float4& w2 = wt[4 * rr + 2];
                const float4& w3 = wt[4 * rr + 3];
                acc[k].x += wv.x * w0.x; acc[k].y += wv.x * w0.y; acc[k].z += wv.x * w0.z; acc[k].w += wv.x * w0.w;
                acc[k].x += wv.y * w1.x; acc[k].y += wv.y * w1.y; acc[k].z += wv.y * w1.z; acc[k].w += wv.y * w1.w;
                acc[k].x += wv.z * w2.x; acc[k].y += wv.z * w2.y; acc[k].z += wv.z * w2.z; acc[k].w += wv.z * w2.w;
                acc[k].x += wv.w * w3.x; acc[k].y += wv.w * w3.y; acc[k].z += wv.w * w3.z; acc[k].w += wv.w * w3.w;
            }
        }
    }

    #pragma unroll
    for (int k = 0; k < 4; ++k) {
        int t = g * TOK_PER_BLK + ts + k * 8;
        *reinterpret_cast<float4*>(&out[t * EMB + c * EMB_CHUNK + eq]) = acc[k];
    }
}

extern "C" void kernel_launch(void* const* d_in, const int* in_sizes, int n_in,
                              void* d_out, int out_size, void* d_ws, size_t ws_size,
                              hipStream_t stream) {
    const float* U0 = (const float*)d_in[0];
    const float* U1 = (const float*)d_in[1];
    const float* U2 = (const float*)d_in[2];
    const float* U3 = (const float*)d_in[3];
    const float* U4 = (const float*)d_in[4];
    const float* U5 = (const float*)d_in[5];
    const int*   x  = (const int*)d_in[6];
    float* out = (float*)d_out;

    // 1024 blocks = 4 emb-chunks x 256 token-groups; 256 threads each.
    cp_embed_kernel<<<dim3(1024), dim3(256), 0, stream>>>(
        U0, U1, U2, U3, U4, U5, x, out);
}